// Round 9
// baseline (1247.476 us; speedup 1.0000x reference)
//
#include <hip/hip_runtime.h>
#include <hip/hip_bf16.h>
#include <cstdint>
#include <cstddef>

// Shapes: B=64, T=512, J=64, D=256, E=128, gdim=8E=1024, gates=4E=512
// ws layout (bytes), total 134,742,016 (~128.5 MiB):
//   [0,           67,108,864)  g as bf16 (32768 x 1024)   -- dead after gemm1
//        aliased: m  bf16 (32768 x 256) at offset 0
//                 m2 bf16 (32768 x 256) at offset 33,554,432
//   [67,108,864, 100,663,296)  pre_f bf16 (32768 x 512)  [cell][gate] layout!
//   [100,663,296,134,217,728)  pre_b bf16 (32768 x 512)  [cell][gate] layout!
//   [134,217,728,...]          gz0, gz1, smax, z  (32768 fp32 each)
// pre layout: pre[row][j*4+q] = gate q (0=i,1=f,2=g,3=o) of cell j.

typedef short short8v __attribute__((ext_vector_type(8)));
typedef float f32x4 __attribute__((ext_vector_type(4)));
typedef unsigned short ushort8v __attribute__((ext_vector_type(8)));
typedef unsigned short ushort4v __attribute__((ext_vector_type(4)));

static __device__ __forceinline__ float bf2f(unsigned short u) {
  return __uint_as_float(((unsigned int)u) << 16);
}
static __device__ __forceinline__ unsigned short f2bf(float f) {  // RNE
  unsigned int u = __float_as_uint(f);
  return (unsigned short)((u + 0x7FFFu + ((u >> 16) & 1u)) >> 16);
}
static __device__ __forceinline__ float fsig(float x) {
  return 1.f / (1.f + __expf(-x));
}
static __device__ __forceinline__ float ftanh(float x) {
  return 1.f - 2.f / (__expf(2.f * x) + 1.f);
}

// ---------------- attention: s, softmax_j, c2q, smax, g[0:768] bf16, gz partial ----
// grid (64, 4)  block 256.  LDS ~133KB -> 1 block/CU.
__global__ __launch_bounds__(256) void attn_kernel(
    const float* __restrict__ c, const float* __restrict__ q,
    const float* __restrict__ wc, const float* __restrict__ bc,
    const float* __restrict__ wq, const float* __restrict__ bq,
    const float* __restrict__ wcq, const float* __restrict__ bcq,
    const float* __restrict__ W0, const float* __restrict__ W1,
    __hip_bfloat16* __restrict__ g, float* __restrict__ smax,
    float* __restrict__ gz0, float* __restrict__ gz1)
{
  __shared__ float qr[64][256];    // j-major (c2q: lanes sweep d, conflict-free)
  __shared__ float qrt[256][64];   // d-major (s-dot: lanes sweep j, conflict-free)
  __shared__ float qwqs[64];
  __shared__ float cwbuf[4][256];  // per-wave c*wcq row (wave-private)
  __shared__ float abuf[4][64];    // per-wave attention weights (wave-private)
  const int b = blockIdx.x;
  const int tid = threadIdx.x;
  for (int e = tid; e < 64 * 256; e += 256) {
    int j = e >> 8, d = e & 255;
    float v = q[((size_t)b * 64 + j) * 256 + d];
    qr[j][d] = v;
    qrt[d][j] = v;
  }
  __syncthreads();
  if (tid < 64) {
    float s = 0.f;
    for (int d = 0; d < 256; ++d) s += qrt[d][tid] * wq[d];
    qwqs[tid] = s + bq[0];
  }
  __syncthreads();
  const int wave = tid >> 6, lane = tid & 63;
  const float bcv = bc[0], bcqv = bcq[0];
  const int t0 = blockIdx.y * 128;
  for (int it = 0; it < 32; ++it) {
    const int trow = t0 + wave + it * 4;
    const float* crow = c + ((size_t)b * 512 + trow) * 256;
    float cv[4];
    float part = 0.f;
    #pragma unroll
    for (int r = 0; r < 4; ++r) {
      int d = lane + 64 * r;
      cv[r] = crow[d];
      cwbuf[wave][d] = cv[r] * wcq[d];
      part += cv[r] * wc[d];
    }
    #pragma unroll
    for (int off = 32; off; off >>= 1) part += __shfl_xor(part, off);
    float s = part + bcv + qwqs[lane] + bcqv;   // lane == j
    #pragma unroll 8
    for (int d = 0; d < 256; ++d) s += cwbuf[wave][d] * qrt[d][lane];
    float mx = s;
    #pragma unroll
    for (int off = 32; off; off >>= 1) mx = fmaxf(mx, __shfl_xor(mx, off));
    float e = expf(s - mx);
    float sum = e;
    #pragma unroll
    for (int off = 32; off; off >>= 1) sum += __shfl_xor(sum, off);
    abuf[wave][lane] = e / sum;
    const size_t grow = (size_t)b * 512 + trow;
    if (lane == 0) smax[grow] = mx;
    size_t row = grow * 1024;
    float az0 = 0.f, az1 = 0.f;
    #pragma unroll
    for (int r = 0; r < 4; ++r) {
      int d = lane + 64 * r;
      float acc = 0.f;
      #pragma unroll 8
      for (int j = 0; j < 64; ++j) acc += abuf[wave][j] * qr[j][d];
      float prod = cv[r] * acc;
      g[row + d]       = __float2bfloat16(cv[r]);
      g[row + 256 + d] = __float2bfloat16(acc);
      g[row + 512 + d] = __float2bfloat16(prod);
      az0 += cv[r] * W0[d] + acc * W0[256 + d] + prod * W0[512 + d];
      az1 += cv[r] * W1[d] + acc * W1[256 + d] + prod * W1[512 + d];
    }
    #pragma unroll
    for (int off = 32; off; off >>= 1) {
      az0 += __shfl_xor(az0, off);
      az1 += __shfl_xor(az1, off);
    }
    if (lane == 0) { gz0[grow] = az0; gz1[grow] = az1; }
  }
}

// ---------------- b_att softmax over t, q2c, g[768:1024] bf16, gz tail ----------
// grid 64, block 256
__global__ __launch_bounds__(256) void batt_kernel(
    const float* __restrict__ c, const float* __restrict__ smax,
    const float* __restrict__ W0, const float* __restrict__ W1,
    __hip_bfloat16* __restrict__ g,
    float* __restrict__ gz0, float* __restrict__ gz1)
{
  __shared__ float sm[512];
  __shared__ float red[4], red2[4];
  __shared__ float q2c_s[256];
  const int b = blockIdx.x, tid = threadIdx.x;
  float v0 = smax[(size_t)b * 512 + tid];
  float v1 = smax[(size_t)b * 512 + tid + 256];
  float m = fmaxf(v0, v1);
  #pragma unroll
  for (int off = 32; off; off >>= 1) m = fmaxf(m, __shfl_xor(m, off));
  if ((tid & 63) == 0) red[tid >> 6] = m;
  __syncthreads();
  float M = fmaxf(fmaxf(red[0], red[1]), fmaxf(red[2], red[3]));
  float e0 = expf(v0 - M), e1 = expf(v1 - M);
  float ssum = e0 + e1;
  #pragma unroll
  for (int off = 32; off; off >>= 1) ssum += __shfl_xor(ssum, off);
  if ((tid & 63) == 0) red2[tid >> 6] = ssum;
  __syncthreads();
  float S = red2[0] + red2[1] + red2[2] + red2[3];
  sm[tid] = e0 / S;
  sm[tid + 256] = e1 / S;
  __syncthreads();
  float acc = 0.f;
  #pragma unroll 8
  for (int t = 0; t < 512; ++t) acc += sm[t] * c[((size_t)b * 512 + t) * 256 + tid];
  q2c_s[tid] = acc;
  __syncthreads();
  const int wave = tid >> 6, lane = tid & 63;
  float qv[4], w0c[4], w1c[4];
  #pragma unroll
  for (int r = 0; r < 4; ++r) {
    int d = lane + 64 * r;
    qv[r]  = q2c_s[d];
    w0c[r] = W0[768 + d];
    w1c[r] = W1[768 + d];
  }
  for (int t = wave; t < 512; t += 4) {
    size_t row = (size_t)b * 512 + t;
    float s0 = 0.f, s1 = 0.f;
    #pragma unroll
    for (int r = 0; r < 4; ++r) {
      int d = lane + 64 * r;
      float v = c[row * 256 + d];
      float gv = v * qv[r];
      g[row * 1024 + 768 + d] = __float2bfloat16(gv);
      s0 += gv * w0c[r];
      s1 += gv * w1c[r];
    }
    #pragma unroll
    for (int off = 32; off; off >>= 1) {
      s0 += __shfl_xor(s0, off);
      s1 += __shfl_xor(s1, off);
    }
    if (lane == 0) { gz0[row] += s0; gz1[row] += s1; }
  }
}

// ---------------- MFMA GEMM: pre[M,512] = Xbf16[M,K] @ Wfp32[512,K]^T + b1 + b2 ---
// grid (M/128, 4), block 256 (4 waves, each 64x64). BK=64. W cvt'd inline.
// Output stored PERMUTED: pre[row][ (col&127)*4 + (col>>7) ]  ([cell][gate]).
__global__ __launch_bounds__(256) void gemm_mfma_kernel(
    const __hip_bfloat16* __restrict__ Xg, const float* __restrict__ W,
    const float* __restrict__ bias1, const float* __restrict__ bias2,
    __hip_bfloat16* __restrict__ Y, int K, int N)
{
  __shared__ unsigned short Xs[128 * 72];  // row stride 72 (+8 pad = 16B, b128-aligned)
  __shared__ unsigned short Ws[128 * 72];
  const unsigned short* X = (const unsigned short*)Xg;
  const int tid = threadIdx.x;
  const int m0 = blockIdx.x * 128, n0 = blockIdx.y * 128;
  const int lane = tid & 63, wave = tid >> 6;
  const int wr = wave >> 1, wc = wave & 1;
  const int frow = lane & 15, fk = (lane >> 4) * 8;

  f32x4 acc[4][4] = {};
  for (int kt = 0; kt < K; kt += 64) {
    #pragma unroll
    for (int i = 0; i < 4; ++i) {
      int cidx = tid + 256 * i;          // 0..1023
      int row = cidx >> 3, kc = cidx & 7;
      ushort8v v = *(const ushort8v*)&X[(size_t)(m0 + row) * K + kt + kc * 8];
      *(ushort8v*)&Xs[row * 72 + kc * 8] = v;
    }
    #pragma unroll
    for (int i = 0; i < 4; ++i) {
      int cidx = tid + 256 * i;
      int row = cidx >> 3, kc = cidx & 7;
      const float* wp = &W[(size_t)(n0 + row) * K + kt + kc * 8];
      float4 f0 = *(const float4*)wp;
      float4 f1 = *(const float4*)(wp + 4);
      ushort8v v;
      v[0] = f2bf(f0.x); v[1] = f2bf(f0.y); v[2] = f2bf(f0.z); v[3] = f2bf(f0.w);
      v[4] = f2bf(f1.x); v[5] = f2bf(f1.y); v[6] = f2bf(f1.z); v[7] = f2bf(f1.w);
      *(ushort8v*)&Ws[row * 72 + kc * 8] = v;
    }
    __syncthreads();
    #pragma unroll
    for (int kk = 0; kk < 64; kk += 32) {
      short8v a[4], bfr[4];
      #pragma unroll
      for (int i = 0; i < 4; ++i)
        a[i] = *(const short8v*)&Xs[(wr * 64 + i * 16 + frow) * 72 + kk + fk];
      #pragma unroll
      for (int j = 0; j < 4; ++j)
        bfr[j] = *(const short8v*)&Ws[(wc * 64 + j * 16 + frow) * 72 + kk + fk];
      #pragma unroll
      for (int i = 0; i < 4; ++i)
        #pragma unroll
        for (int j = 0; j < 4; ++j)
          acc[i][j] = __builtin_amdgcn_mfma_f32_16x16x32_bf16(a[i], bfr[j], acc[i][j], 0, 0, 0);
    }
    __syncthreads();
  }
  const int r0 = (lane >> 4) * 4;
  #pragma unroll
  for (int j = 0; j < 4; ++j) {
    int col = n0 + wc * 64 + j * 16 + (lane & 15);
    int colp = (col & 127) * 4 + (col >> 7);   // [cell][gate] permuted layout
    float bsum = bias1[col] + bias2[col];
    #pragma unroll
    for (int i = 0; i < 4; ++i) {
      int rowb = m0 + wr * 64 + i * 16 + r0;
      #pragma unroll
      for (int r = 0; r < 4; ++r)
        Y[(size_t)(rowb + r) * N + colp] = __float2bfloat16(acc[i][j][r] + bsum);
    }
  }
}

// ---------------- LSTM recurrence via MFMA, 8-step chunked I/O ----------------
// grid (64, 2) block 512 (8 waves). Per step per wave: 4 ds_read_b128 (h bcast)
// + 16 MFMA (8 independent chains of depth 2, r9) + kg-split activations (r9).
// VMEM chunked (r8): 8 pre loads at chunk top, 8 h stores at chunk end.
// kg-split: lane in k-group g activates only gate g of its cell; lane<16
// gathers i,f,g,o via 4 __shfl and runs the cst/h tail alone.
__global__ __launch_bounds__(512, 2) void lstm_kernel(
    const __hip_bfloat16* __restrict__ pre_f, const __hip_bfloat16* __restrict__ pre_b,
    const float* __restrict__ Whh_f, const float* __restrict__ Whh_b,
    __hip_bfloat16* __restrict__ out)
{
  const int b = blockIdx.x, dir = blockIdx.y;
  const unsigned short* __restrict__ pre =
      (const unsigned short*)(dir ? pre_b : pre_f);
  const float* __restrict__ Whh = dir ? Whh_b : Whh_f;
  const int off = dir ? 128 : 0;
  const int tid = threadIdx.x;
  const int wave = tid >> 6, lane = tid & 63;
  const int cl = lane & 15;            // col / cell-within-wave
  const int kg = lane >> 4;            // k-group 0..3
  const int cell = wave * 16 + cl;     // 0..127

  // B fragments (16 named vars): bfQ_T = Whh[q*128+cell][kt*32 + kg*8 .. +8]
#define LOAD_BF(Q, T, DST)                                            \
  {                                                                   \
    const float* wp = Whh + (size_t)(Q * 128 + cell) * 128 + T * 32 + kg * 8; \
    float4 f0 = *(const float4*)wp;                                   \
    float4 f1 = *(const float4*)(wp + 4);                             \
    DST[0] = (short)f2bf(f0.x); DST[1] = (short)f2bf(f0.y);           \
    DST[2] = (short)f2bf(f0.z); DST[3] = (short)f2bf(f0.w);           \
    DST[4] = (short)f2bf(f1.x); DST[5] = (short)f2bf(f1.y);           \
    DST[6] = (short)f2bf(f1.z); DST[7] = (short)f2bf(f1.w);           \
    asm volatile("" : "+v"(DST));                                     \
  }
  short8v bf00, bf01, bf02, bf03, bf10, bf11, bf12, bf13;
  short8v bf20, bf21, bf22, bf23, bf30, bf31, bf32, bf33;
  LOAD_BF(0, 0, bf00) LOAD_BF(0, 1, bf01) LOAD_BF(0, 2, bf02) LOAD_BF(0, 3, bf03)
  LOAD_BF(1, 0, bf10) LOAD_BF(1, 1, bf11) LOAD_BF(1, 2, bf12) LOAD_BF(1, 3, bf13)
  LOAD_BF(2, 0, bf20) LOAD_BF(2, 1, bf21) LOAD_BF(2, 2, bf22) LOAD_BF(2, 3, bf23)
  LOAD_BF(3, 0, bf30) LOAD_BF(3, 1, bf31) LOAD_BF(3, 2, bf32) LOAD_BF(3, 3, bf33)
#undef LOAD_BF

  __shared__ unsigned short hbuf[2][128];   // h as bf16, double-buffered
  if (tid < 128) { hbuf[0][tid] = 0; hbuf[1][tid] = 0; }
  __syncthreads();

  const size_t base = (size_t)b * 512;
  const int tstep = dir ? -1 : 1;
  const int t0 = dir ? 511 : 0;
  const unsigned short* prow = pre + base * 512 + cell * 4;         // + t*512
  unsigned short* orow = (unsigned short*)out + base * 256 + off + cell;  // + t*256

  int cur = 0;
  float cst = 0.f;
  // 8 independent accumulator chains (2 per gate, depth 2); rows 1-3 garbage.
  f32x4 acc0a = {0.f, 0.f, 0.f, 0.f};
  f32x4 acc1a = acc0a, acc2a = acc0a, acc3a = acc0a;
  f32x4 acc0b = acc0a, acc1b = acc0a, acc2b = acc0a, acc3b = acc0a;

#define LSTM_STEP(P, HOUT)                                                   \
  {                                                                          \
    const unsigned short* hb = hbuf[cur];                                    \
    short8v a0 = *(const short8v*)(hb +  0 + kg * 8);                        \
    short8v a1 = *(const short8v*)(hb + 32 + kg * 8);                        \
    short8v a2 = *(const short8v*)(hb + 64 + kg * 8);                        \
    short8v a3 = *(const short8v*)(hb + 96 + kg * 8);                        \
    acc0a[0] = bf2f(P[0]); acc1a[0] = bf2f(P[1]);                            \
    acc2a[0] = bf2f(P[2]); acc3a[0] = bf2f(P[3]);                            \
    acc0b[0] = 0.f; acc1b[0] = 0.f; acc2b[0] = 0.f; acc3b[0] = 0.f;          \
    acc0a = __builtin_amdgcn_mfma_f32_16x16x32_bf16(a0, bf00, acc0a, 0, 0, 0);\
    acc1a = __builtin_amdgcn_mfma_f32_16x16x32_bf16(a0, bf10, acc1a, 0, 0, 0);\
    acc2a = __builtin_amdgcn_mfma_f32_16x16x32_bf16(a0, bf20, acc2a, 0, 0, 0);\
    acc3a = __builtin_amdgcn_mfma_f32_16x16x32_bf16(a0, bf30, acc3a, 0, 0, 0);\
    acc0b = __builtin_amdgcn_mfma_f32_16x16x32_bf16(a2, bf02, acc0b, 0, 0, 0);\
    acc1b = __builtin_amdgcn_mfma_f32_16x16x32_bf16(a2, bf12, acc1b, 0, 0, 0);\
    acc2b = __builtin_amdgcn_mfma_f32_16x16x32_bf16(a2, bf22, acc2b, 0, 0, 0);\
    acc3b = __builtin_amdgcn_mfma_f32_16x16x32_bf16(a2, bf32, acc3b, 0, 0, 0);\
    acc0a = __builtin_amdgcn_mfma_f32_16x16x32_bf16(a1, bf01, acc0a, 0, 0, 0);\
    acc1a = __builtin_amdgcn_mfma_f32_16x16x32_bf16(a1, bf11, acc1a, 0, 0, 0);\
    acc2a = __builtin_amdgcn_mfma_f32_16x16x32_bf16(a1, bf21, acc2a, 0, 0, 0);\
    acc3a = __builtin_amdgcn_mfma_f32_16x16x32_bf16(a1, bf31, acc3a, 0, 0, 0);\
    acc0b = __builtin_amdgcn_mfma_f32_16x16x32_bf16(a3, bf03, acc0b, 0, 0, 0);\
    acc1b = __builtin_amdgcn_mfma_f32_16x16x32_bf16(a3, bf13, acc1b, 0, 0, 0);\
    acc2b = __builtin_amdgcn_mfma_f32_16x16x32_bf16(a3, bf23, acc2b, 0, 0, 0);\
    acc3b = __builtin_amdgcn_mfma_f32_16x16x32_bf16(a3, bf33, acc3b, 0, 0, 0);\
    float x0 = acc0a[0] + acc0b[0];                                          \
    float x1 = acc1a[0] + acc1b[0];                                          \
    float x2 = acc2a[0] + acc2b[0];                                          \
    float x3 = acc3a[0] + acc3b[0];                                          \
    float xs = (kg == 0) ? x0 : (kg == 1) ? x1 : (kg == 2) ? x2 : x3;        \
    float av = (kg == 2) ? ftanh(xs) : fsig(xs);                             \
    float gi_ = __shfl(av, cl);                                              \
    float gf_ = __shfl(av, cl + 16);                                         \
    float gg_ = __shfl(av, cl + 32);                                         \
    float go_ = __shfl(av, cl + 48);                                         \
    if (lane < 16) {                                                         \
      cst = gf_ * cst + gi_ * gg_;                                           \
      float hv = go_ * ftanh(cst);                                           \
      HOUT = f2bf(hv);                                                       \
      hbuf[cur ^ 1][cell] = HOUT;                                            \
    }                                                                        \
    __syncthreads();                                                         \
    cur ^= 1;                                                                \
  }

  for (int chunk = 0; chunk < 64; ++chunk) {
    const int tb = t0 + chunk * 8 * tstep;   // first t of this chunk
    ushort4v p0 = *(const ushort4v*)(prow + (size_t)(tb)             * 512);
    ushort4v p1 = *(const ushort4v*)(prow + (size_t)(tb + 1 * tstep) * 512);
    ushort4v p2 = *(const ushort4v*)(prow + (size_t)(tb + 2 * tstep) * 512);
    ushort4v p3 = *(const ushort4v*)(prow + (size_t)(tb + 3 * tstep) * 512);
    ushort4v p4 = *(const ushort4v*)(prow + (size_t)(tb + 4 * tstep) * 512);
    ushort4v p5 = *(const ushort4v*)(prow + (size_t)(tb + 5 * tstep) * 512);
    ushort4v p6 = *(const ushort4v*)(prow + (size_t)(tb + 6 * tstep) * 512);
    ushort4v p7 = *(const ushort4v*)(prow + (size_t)(tb + 7 * tstep) * 512);
    unsigned short h0 = 0, h1 = 0, h2 = 0, h3 = 0, h4 = 0, h5 = 0, h6 = 0, h7 = 0;
    LSTM_STEP(p0, h0)
    LSTM_STEP(p1, h1)
    LSTM_STEP(p2, h2)
    LSTM_STEP(p3, h3)
    LSTM_STEP(p4, h4)
    LSTM_STEP(p5, h5)
    LSTM_STEP(p6, h6)
    LSTM_STEP(p7, h7)
    if (lane < 16) {
      orow[(size_t)(tb)             * 256] = h0;
      orow[(size_t)(tb + 1 * tstep) * 256] = h1;
      orow[(size_t)(tb + 2 * tstep) * 256] = h2;
      orow[(size_t)(tb + 3 * tstep) * 256] = h3;
      orow[(size_t)(tb + 4 * tstep) * 256] = h4;
      orow[(size_t)(tb + 5 * tstep) * 256] = h5;
      orow[(size_t)(tb + 6 * tstep) * 256] = h6;
      orow[(size_t)(tb + 7 * tstep) * 256] = h7;
    }
  }
#undef LSTM_STEP
}

// ---------------- logits: z[row] = gz[row] + m_row(bf16) . W[1024:1280] + bias ----
// grid 8192, block 256 (wave per row)
__global__ __launch_bounds__(256) void logits_kernel(
    const __hip_bfloat16* __restrict__ m, const float* __restrict__ W,
    const float* __restrict__ bias, const float* __restrict__ gz,
    float* __restrict__ z)
{
  const int row = blockIdx.x * 4 + (threadIdx.x >> 6);
  const int lane = threadIdx.x & 63;
  const unsigned short* mrow = (const unsigned short*)m + (size_t)row * 256;
  float acc = 0.f;
  #pragma unroll
  for (int i = 0; i < 4; ++i) acc += bf2f(mrow[lane + 64 * i]) * W[1024 + lane + 64 * i];
  #pragma unroll
  for (int off = 32; off; off >>= 1) acc += __shfl_xor(acc, off);
  if (lane == 0) z[row] = acc + gz[row] + bias[0];
}

// ---------------- softmax over t ----------------
// grid 64, block 512
__global__ __launch_bounds__(512) void softmax_t_kernel(
    const float* __restrict__ z, float* __restrict__ p)
{
  const int b = blockIdx.x, t = threadIdx.x;
  __shared__ float red[8], red2[8];
  float v = z[(size_t)b * 512 + t];
  float m = v;
  #pragma unroll
  for (int off = 32; off; off >>= 1) m = fmaxf(m, __shfl_xor(m, off));
  if ((t & 63) == 0) red[t >> 6] = m;
  __syncthreads();
  float M = red[0];
  #pragma unroll
  for (int i = 1; i < 8; ++i) M = fmaxf(M, red[i]);
  float e = expf(v - M);
  float s = e;
  #pragma unroll
  for (int off = 32; off; off >>= 1) s += __shfl_xor(s, off);
  if ((t & 63) == 0) red2[t >> 6] = s;
  __syncthreads();
  float S = red2[0];
  #pragma unroll
  for (int i = 1; i < 8; ++i) S += red2[i];
  p[(size_t)b * 512 + t] = e / S;
}

extern "C" void kernel_launch(void* const* d_in, const int* in_sizes, int n_in,
                              void* d_out, int out_size, void* d_ws, size_t ws_size,
                              hipStream_t stream)
{
  const float* c   = (const float*)d_in[0];
  const float* q   = (const float*)d_in[1];
  const float* wc  = (const float*)d_in[2];
  const float* bc  = (const float*)d_in[3];
  const float* wq  = (const float*)d_in[4];
  const float* bq  = (const float*)d_in[5];
  const float* wcq = (const float*)d_in[6];
  const float* bcq = (const float*)d_in[7];
  const float* l1f_Wih = (const float*)d_in[8];
  const float* l1f_Whh = (const float*)d_in[9];
  const float* l1f_bih = (const float*)d_in[10];
  const float* l1f_bhh = (const float*)d_in[11];
  const float* l1b_Wih = (const float*)d_in[12];
  const float* l1b_Whh = (const float*)d_in[13];
  const float* l1b_bih = (const float*)d_in[14];
  const float* l1b_bhh = (const float*)d_in[15];
  const float* l2f_Wih = (const float*)d_in[16];
  const float* l2f_Whh = (const float*)d_in[17];
  const float* l2f_bih = (const float*)d_in[18];
  const float* l2f_bhh = (const float*)d_in[19];
  const float* l2b_Wih = (const float*)d_in[20];
  const float* l2b_Whh = (const float*)d_in[21];
  const float* l2b_bih = (const float*)d_in[22];
  const float* l2b_bhh = (const float*)d_in[23];
  const float* W0 = (const float*)d_in[24];
  const float* b0 = (const float*)d_in[25];
  const float* W1 = (const float*)d_in[26];
  const float* b1 = (const float*)d_in[27];

  const size_t required = 134742016u;
  if (ws_size < required) return;

  char* wsb = (char*)d_ws;
  __hip_bfloat16* gbf = (__hip_bfloat16*)wsb;                  // 67,108,864 B
  __hip_bfloat16* m   = (__hip_bfloat16*)wsb;                  // alias (g dead after gemm1)
  __hip_bfloat16* m2  = (__hip_bfloat16*)(wsb + 33554432);     // alias
  __hip_bfloat16* pref = (__hip_bfloat16*)(wsb + 67108864);    // 33,554,432 B
  __hip_bfloat16* preb = (__hip_bfloat16*)(wsb + 100663296);   // 33,554,432 B
  float* gz0  = (float*)(wsb + 134217728);
  float* gz1  = gz0 + 32768;
  float* smax = gz1 + 32768;
  float* z    = smax + 32768;
  float* p1   = (float*)d_out;
  float* p2   = p1 + 32768;

  attn_kernel<<<dim3(64, 4), 256, 0, stream>>>(c, q, wc, bc, wq, bq, wcq, bcq,
                                               W0, W1, gbf, smax, gz0, gz1);
  batt_kernel<<<64, 256, 0, stream>>>(c, smax, W0, W1, gbf, gz0, gz1);

  gemm_mfma_kernel<<<dim3(256, 4), 256, 0, stream>>>(gbf, l1f_Wih, l1f_bih, l1f_bhh, pref, 1024, 512);
  gemm_mfma_kernel<<<dim3(256, 4), 256, 0, stream>>>(gbf, l1b_Wih, l1b_bih, l1b_bhh, preb, 1024, 512);
  lstm_kernel<<<dim3(64, 2), 512, 0, stream>>>(pref, preb, l1f_Whh, l1b_Whh, m);

  logits_kernel<<<8192, 256, 0, stream>>>(m, W0, b0, gz0, z);
  softmax_t_kernel<<<64, 512, 0, stream>>>(z, p1);

  gemm_mfma_kernel<<<dim3(256, 4), 256, 0, stream>>>(m, l2f_Wih, l2f_bih, l2f_bhh, pref, 256, 512);
  gemm_mfma_kernel<<<dim3(256, 4), 256, 0, stream>>>(m, l2b_Wih, l2b_bih, l2b_bhh, preb, 256, 512);
  lstm_kernel<<<dim3(64, 2), 512, 0, stream>>>(pref, preb, l2f_Whh, l2b_Whh, m2);

  logits_kernel<<<8192, 256, 0, stream>>>(m2, W1, b1, gz1, z);
  softmax_t_kernel<<<64, 512, 0, stream>>>(z, p2);
}

// Round 10
// 1174.978 us; speedup vs baseline: 1.0617x; 1.0617x over previous
//
#include <hip/hip_runtime.h>
#include <hip/hip_bf16.h>
#include <cstdint>
#include <cstddef>

// Shapes: B=64, T=512, J=64, D=256, E=128, gdim=8E=1024, gates=4E=512
// ws layout (bytes), total 137,371,648 (~131 MiB):
//   [0,           67,108,864)  g bf16 (32768 x 1024)   -- dead after gemm1
//        aliased: m  bf16 (32768 x 256) at 0 ; m2 bf16 at 33,554,432
//   [67,108,864, 100,663,296)  pre_f bf16 (32768 x 512)  [cell][gate] layout
//   [100,663,296,134,217,728)  pre_b bf16 (32768 x 512)  [cell][gate] layout
//   [134,217,728,134,742,016)  gz0, gz1, smax, z (32768 fp32 each)
//   [134,742,016,135,790,592)  w1f bf16 (512x1024)
//   [135,790,592,136,839,168)  w1b bf16
//   [136,839,168,137,101,312)  w2f bf16 (512x256)
//   [137,101,312,137,363,456)  w2b bf16
//   [137,363,456,137,371,648)  bs[4][512] fp32 (bih+bhh, l1f/l1b/l2f/l2b)

typedef short short8v __attribute__((ext_vector_type(8)));
typedef float f32x4 __attribute__((ext_vector_type(4)));
typedef unsigned short ushort8v __attribute__((ext_vector_type(8)));
typedef unsigned short ushort4v __attribute__((ext_vector_type(4)));

static __device__ __forceinline__ float bf2f(unsigned short u) {
  return __uint_as_float(((unsigned int)u) << 16);
}
static __device__ __forceinline__ unsigned short f2bf(float f) {  // RNE
  unsigned int u = __float_as_uint(f);
  return (unsigned short)((u + 0x7FFFu + ((u >> 16) & 1u)) >> 16);
}
static __device__ __forceinline__ float fsig(float x) {
  return 1.f / (1.f + __expf(-x));
}
static __device__ __forceinline__ float ftanh(float x) {
  return 1.f - 2.f / (__expf(2.f * x) + 1.f);
}

// ---------------- weight pre-convert: 4x Wih fp32->bf16, bias sums ----------
// grid 1288 x 256. blocks 0..1279: 4 floats/thread over virtual concat
// [w1f 524288 | w1b 524288 | w2f 131072 | w2b 131072]; blocks 1280..1287: bias.
__global__ __launch_bounds__(256) void cvt_w_kernel(
    const float* __restrict__ w1f, const float* __restrict__ w1b,
    const float* __restrict__ w2f, const float* __restrict__ w2b,
    const float* __restrict__ b1fi, const float* __restrict__ b1fh,
    const float* __restrict__ b1bi, const float* __restrict__ b1bh,
    const float* __restrict__ b2fi, const float* __restrict__ b2fh,
    const float* __restrict__ b2bi, const float* __restrict__ b2bh,
    unsigned short* __restrict__ d1f, unsigned short* __restrict__ d1b,
    unsigned short* __restrict__ d2f, unsigned short* __restrict__ d2b,
    float* __restrict__ bs)
{
  const int bid = blockIdx.x, tid = threadIdx.x;
  if (bid < 1280) {
    int idx = (bid * 256 + tid) * 4;
    const float* src;
    unsigned short* dst;
    int off;
    if (idx < 524288)        { src = w1f; dst = d1f; off = idx; }
    else if (idx < 1048576)  { src = w1b; dst = d1b; off = idx - 524288; }
    else if (idx < 1179648)  { src = w2f; dst = d2f; off = idx - 1048576; }
    else                     { src = w2b; dst = d2b; off = idx - 1179648; }
    float4 f = *(const float4*)(src + off);
    ushort4v v;
    v[0] = f2bf(f.x); v[1] = f2bf(f.y); v[2] = f2bf(f.z); v[3] = f2bf(f.w);
    *(ushort4v*)(dst + off) = v;
  } else {
    int bidx = (bid - 1280) * 256 + tid;   // 0..2047
    int which = bidx >> 9, col = bidx & 511;
    float v;
    if (which == 0)      v = b1fi[col] + b1fh[col];
    else if (which == 1) v = b1bi[col] + b1bh[col];
    else if (which == 2) v = b2fi[col] + b2fh[col];
    else                 v = b2bi[col] + b2bh[col];
    bs[bidx] = v;
  }
}

// ---------------- attention: s, softmax_j, c2q, smax, g[0:768] bf16, gz partial ----
// grid (64, 4)  block 256.  LDS ~133KB -> 1 block/CU.
__global__ __launch_bounds__(256) void attn_kernel(
    const float* __restrict__ c, const float* __restrict__ q,
    const float* __restrict__ wc, const float* __restrict__ bc,
    const float* __restrict__ wq, const float* __restrict__ bq,
    const float* __restrict__ wcq, const float* __restrict__ bcq,
    const float* __restrict__ W0, const float* __restrict__ W1,
    __hip_bfloat16* __restrict__ g, float* __restrict__ smax,
    float* __restrict__ gz0, float* __restrict__ gz1)
{
  __shared__ float qr[64][256];    // j-major (c2q: lanes sweep d, conflict-free)
  __shared__ float qrt[256][64];   // d-major (s-dot: lanes sweep j, conflict-free)
  __shared__ float qwqs[64];
  __shared__ float cwbuf[4][256];  // per-wave c*wcq row (wave-private)
  __shared__ float abuf[4][64];    // per-wave attention weights (wave-private)
  const int b = blockIdx.x;
  const int tid = threadIdx.x;
  for (int e = tid; e < 64 * 256; e += 256) {
    int j = e >> 8, d = e & 255;
    float v = q[((size_t)b * 64 + j) * 256 + d];
    qr[j][d] = v;
    qrt[d][j] = v;
  }
  __syncthreads();
  if (tid < 64) {
    float s = 0.f;
    for (int d = 0; d < 256; ++d) s += qrt[d][tid] * wq[d];
    qwqs[tid] = s + bq[0];
  }
  __syncthreads();
  const int wave = tid >> 6, lane = tid & 63;
  const float bcv = bc[0], bcqv = bcq[0];
  const int t0 = blockIdx.y * 128;
  for (int it = 0; it < 32; ++it) {
    const int trow = t0 + wave + it * 4;
    const float* crow = c + ((size_t)b * 512 + trow) * 256;
    float cv[4];
    float part = 0.f;
    #pragma unroll
    for (int r = 0; r < 4; ++r) {
      int d = lane + 64 * r;
      cv[r] = crow[d];
      cwbuf[wave][d] = cv[r] * wcq[d];
      part += cv[r] * wc[d];
    }
    #pragma unroll
    for (int off = 32; off; off >>= 1) part += __shfl_xor(part, off);
    float s = part + bcv + qwqs[lane] + bcqv;   // lane == j
    #pragma unroll 8
    for (int d = 0; d < 256; ++d) s += cwbuf[wave][d] * qrt[d][lane];
    float mx = s;
    #pragma unroll
    for (int off = 32; off; off >>= 1) mx = fmaxf(mx, __shfl_xor(mx, off));
    float e = expf(s - mx);
    float sum = e;
    #pragma unroll
    for (int off = 32; off; off >>= 1) sum += __shfl_xor(sum, off);
    abuf[wave][lane] = e / sum;
    const size_t grow = (size_t)b * 512 + trow;
    if (lane == 0) smax[grow] = mx;
    size_t row = grow * 1024;
    float az0 = 0.f, az1 = 0.f;
    #pragma unroll
    for (int r = 0; r < 4; ++r) {
      int d = lane + 64 * r;
      float acc = 0.f;
      #pragma unroll 8
      for (int j = 0; j < 64; ++j) acc += abuf[wave][j] * qr[j][d];
      float prod = cv[r] * acc;
      g[row + d]       = __float2bfloat16(cv[r]);
      g[row + 256 + d] = __float2bfloat16(acc);
      g[row + 512 + d] = __float2bfloat16(prod);
      az0 += cv[r] * W0[d] + acc * W0[256 + d] + prod * W0[512 + d];
      az1 += cv[r] * W1[d] + acc * W1[256 + d] + prod * W1[512 + d];
    }
    #pragma unroll
    for (int off = 32; off; off >>= 1) {
      az0 += __shfl_xor(az0, off);
      az1 += __shfl_xor(az1, off);
    }
    if (lane == 0) { gz0[grow] = az0; gz1[grow] = az1; }
  }
}

// ---------------- b_att softmax over t, q2c, g[768:1024] bf16, gz tail ----------
// grid 64, block 256
__global__ __launch_bounds__(256) void batt_kernel(
    const float* __restrict__ c, const float* __restrict__ smax,
    const float* __restrict__ W0, const float* __restrict__ W1,
    __hip_bfloat16* __restrict__ g,
    float* __restrict__ gz0, float* __restrict__ gz1)
{
  __shared__ float sm[512];
  __shared__ float red[4], red2[4];
  __shared__ float q2c_s[256];
  const int b = blockIdx.x, tid = threadIdx.x;
  float v0 = smax[(size_t)b * 512 + tid];
  float v1 = smax[(size_t)b * 512 + tid + 256];
  float m = fmaxf(v0, v1);
  #pragma unroll
  for (int off = 32; off; off >>= 1) m = fmaxf(m, __shfl_xor(m, off));
  if ((tid & 63) == 0) red[tid >> 6] = m;
  __syncthreads();
  float M = fmaxf(fmaxf(red[0], red[1]), fmaxf(red[2], red[3]));
  float e0 = expf(v0 - M), e1 = expf(v1 - M);
  float ssum = e0 + e1;
  #pragma unroll
  for (int off = 32; off; off >>= 1) ssum += __shfl_xor(ssum, off);
  if ((tid & 63) == 0) red2[tid >> 6] = ssum;
  __syncthreads();
  float S = red2[0] + red2[1] + red2[2] + red2[3];
  sm[tid] = e0 / S;
  sm[tid + 256] = e1 / S;
  __syncthreads();
  float acc = 0.f;
  #pragma unroll 8
  for (int t = 0; t < 512; ++t) acc += sm[t] * c[((size_t)b * 512 + t) * 256 + tid];
  q2c_s[tid] = acc;
  __syncthreads();
  const int wave = tid >> 6, lane = tid & 63;
  float qv[4], w0c[4], w1c[4];
  #pragma unroll
  for (int r = 0; r < 4; ++r) {
    int d = lane + 64 * r;
    qv[r]  = q2c_s[d];
    w0c[r] = W0[768 + d];
    w1c[r] = W1[768 + d];
  }
  for (int t = wave; t < 512; t += 4) {
    size_t row = (size_t)b * 512 + t;
    float s0 = 0.f, s1 = 0.f;
    #pragma unroll
    for (int r = 0; r < 4; ++r) {
      int d = lane + 64 * r;
      float v = c[row * 256 + d];
      float gv = v * qv[r];
      g[row * 1024 + 768 + d] = __float2bfloat16(gv);
      s0 += gv * w0c[r];
      s1 += gv * w1c[r];
    }
    #pragma unroll
    for (int off = 32; off; off >>= 1) {
      s0 += __shfl_xor(s0, off);
      s1 += __shfl_xor(s1, off);
    }
    if (lane == 0) { gz0[row] += s0; gz1[row] += s1; }
  }
}

// ---------------- MFMA GEMM: pre[M,512] = Xbf16[M,K] @ Wbf16[512,K]^T + bs ------
// grid (M/128, 4, 2), block 256 (4 waves, each 64x64). BK=64. z picks f/b dir.
// W pre-converted bf16 (cvt_w_kernel) -> staging is pure ushort8 copies.
// Output PERMUTED: pre[row][(col&127)*4 + (col>>7)]  ([cell][gate]).
__global__ __launch_bounds__(256) void gemm_mfma_kernel(
    const __hip_bfloat16* __restrict__ Xg,
    const unsigned short* __restrict__ Wf, const unsigned short* __restrict__ Wb,
    const float* __restrict__ bsf, const float* __restrict__ bsb,
    __hip_bfloat16* __restrict__ Yf, __hip_bfloat16* __restrict__ Yb, int K)
{
  __shared__ unsigned short Xs[128 * 72];  // row stride 72 (+8 pad, b128-aligned)
  __shared__ unsigned short Ws[128 * 72];
  const unsigned short* X = (const unsigned short*)Xg;
  const unsigned short* W = blockIdx.z ? Wb : Wf;
  const float* bs = blockIdx.z ? bsb : bsf;
  __hip_bfloat16* Y = blockIdx.z ? Yb : Yf;
  const int tid = threadIdx.x;
  const int m0 = blockIdx.x * 128, n0 = blockIdx.y * 128;
  const int lane = tid & 63, wave = tid >> 6;
  const int wr = wave >> 1, wc = wave & 1;
  const int frow = lane & 15, fk = (lane >> 4) * 8;

  f32x4 acc[4][4] = {};
  for (int kt = 0; kt < K; kt += 64) {
    #pragma unroll
    for (int i = 0; i < 4; ++i) {
      int cidx = tid + 256 * i;          // 0..1023
      int row = cidx >> 3, kc = cidx & 7;
      *(ushort8v*)&Xs[row * 72 + kc * 8] =
          *(const ushort8v*)&X[(size_t)(m0 + row) * K + kt + kc * 8];
      *(ushort8v*)&Ws[row * 72 + kc * 8] =
          *(const ushort8v*)&W[(size_t)(n0 + row) * K + kt + kc * 8];
    }
    __syncthreads();
    #pragma unroll
    for (int kk = 0; kk < 64; kk += 32) {
      short8v a[4], bfr[4];
      #pragma unroll
      for (int i = 0; i < 4; ++i)
        a[i] = *(const short8v*)&Xs[(wr * 64 + i * 16 + frow) * 72 + kk + fk];
      #pragma unroll
      for (int j = 0; j < 4; ++j)
        bfr[j] = *(const short8v*)&Ws[(wc * 64 + j * 16 + frow) * 72 + kk + fk];
      #pragma unroll
      for (int i = 0; i < 4; ++i)
        #pragma unroll
        for (int j = 0; j < 4; ++j)
          acc[i][j] = __builtin_amdgcn_mfma_f32_16x16x32_bf16(a[i], bfr[j], acc[i][j], 0, 0, 0);
    }
    __syncthreads();
  }
  const int r0 = (lane >> 4) * 4;
  #pragma unroll
  for (int j = 0; j < 4; ++j) {
    int col = n0 + wc * 64 + j * 16 + (lane & 15);
    int colp = (col & 127) * 4 + (col >> 7);   // [cell][gate] permuted layout
    float bsum = bs[col];
    #pragma unroll
    for (int i = 0; i < 4; ++i) {
      int rowb = m0 + wr * 64 + i * 16 + r0;
      #pragma unroll
      for (int r = 0; r < 4; ++r)
        Y[(size_t)(rowb + r) * 512 + colp] = __float2bfloat16(acc[i][j][r] + bsum);
    }
  }
}

// ---------------- LSTM recurrence via MFMA, 8-step chunked I/O (r8 winner) ----
// grid (64, 2) block 512 (8 waves). Per step per wave: 4 ds_read_b128 (h bcast)
// + 16 MFMA + replicated activations; __syncthreads per step. VMEM chunked:
// 8 pre loads at chunk top, 8 h stores at chunk end. Whh converted fp32->bf16
// in-kernel (convert-chain defeats remat -- r4/r5 lesson; keep!), asm-pinned.
__global__ __launch_bounds__(512, 2) void lstm_kernel(
    const __hip_bfloat16* __restrict__ pre_f, const __hip_bfloat16* __restrict__ pre_b,
    const float* __restrict__ Whh_f, const float* __restrict__ Whh_b,
    __hip_bfloat16* __restrict__ out)
{
  const int b = blockIdx.x, dir = blockIdx.y;
  const unsigned short* __restrict__ pre =
      (const unsigned short*)(dir ? pre_b : pre_f);
  const float* __restrict__ Whh = dir ? Whh_b : Whh_f;
  const int off = dir ? 128 : 0;
  const int tid = threadIdx.x;
  const int wave = tid >> 6, lane = tid & 63;
  const int cl = lane & 15;            // col / cell-within-wave
  const int kg = lane >> 4;            // k-group 0..3
  const int cell = wave * 16 + cl;     // 0..127

#define LOAD_BF(Q, T, DST)                                            \
  {                                                                   \
    const float* wp = Whh + (size_t)(Q * 128 + cell) * 128 + T * 32 + kg * 8; \
    float4 f0 = *(const float4*)wp;                                   \
    float4 f1 = *(const float4*)(wp + 4);                             \
    DST[0] = (short)f2bf(f0.x); DST[1] = (short)f2bf(f0.y);           \
    DST[2] = (short)f2bf(f0.z); DST[3] = (short)f2bf(f0.w);           \
    DST[4] = (short)f2bf(f1.x); DST[5] = (short)f2bf(f1.y);           \
    DST[6] = (short)f2bf(f1.z); DST[7] = (short)f2bf(f1.w);           \
    asm volatile("" : "+v"(DST));                                     \
  }
  short8v bf00, bf01, bf02, bf03, bf10, bf11, bf12, bf13;
  short8v bf20, bf21, bf22, bf23, bf30, bf31, bf32, bf33;
  LOAD_BF(0, 0, bf00) LOAD_BF(0, 1, bf01) LOAD_BF(0, 2, bf02) LOAD_BF(0, 3, bf03)
  LOAD_BF(1, 0, bf10) LOAD_BF(1, 1, bf11) LOAD_BF(1, 2, bf12) LOAD_BF(1, 3, bf13)
  LOAD_BF(2, 0, bf20) LOAD_BF(2, 1, bf21) LOAD_BF(2, 2, bf22) LOAD_BF(2, 3, bf23)
  LOAD_BF(3, 0, bf30) LOAD_BF(3, 1, bf31) LOAD_BF(3, 2, bf32) LOAD_BF(3, 3, bf33)
#undef LOAD_BF

  __shared__ unsigned short hbuf[2][128];   // h as bf16, double-buffered
  if (tid < 128) { hbuf[0][tid] = 0; hbuf[1][tid] = 0; }
  __syncthreads();

  const size_t base = (size_t)b * 512;
  const int tstep = dir ? -1 : 1;
  const int t0 = dir ? 511 : 0;
  const unsigned short* prow = pre + base * 512 + cell * 4;
  unsigned short* orow = (unsigned short*)out + base * 256 + off + cell;

  int cur = 0;
  float cst = 0.f;
  f32x4 acc0 = {0.f, 0.f, 0.f, 0.f};
  f32x4 acc1 = acc0, acc2 = acc0, acc3 = acc0;

#define LSTM_STEP(P, HOUT)                                                  \
  {                                                                         \
    const unsigned short* hb = hbuf[cur];                                   \
    short8v a0 = *(const short8v*)(hb +  0 + kg * 8);                       \
    short8v a1 = *(const short8v*)(hb + 32 + kg * 8);                       \
    short8v a2 = *(const short8v*)(hb + 64 + kg * 8);                       \
    short8v a3 = *(const short8v*)(hb + 96 + kg * 8);                       \
    acc0[0] = bf2f(P[0]); acc1[0] = bf2f(P[1]);                             \
    acc2[0] = bf2f(P[2]); acc3[0] = bf2f(P[3]);                             \
    acc0 = __builtin_amdgcn_mfma_f32_16x16x32_bf16(a0, bf00, acc0, 0, 0, 0);\
    acc1 = __builtin_amdgcn_mfma_f32_16x16x32_bf16(a0, bf10, acc1, 0, 0, 0);\
    acc2 = __builtin_amdgcn_mfma_f32_16x16x32_bf16(a0, bf20, acc2, 0, 0, 0);\
    acc3 = __builtin_amdgcn_mfma_f32_16x16x32_bf16(a0, bf30, acc3, 0, 0, 0);\
    acc0 = __builtin_amdgcn_mfma_f32_16x16x32_bf16(a1, bf01, acc0, 0, 0, 0);\
    acc1 = __builtin_amdgcn_mfma_f32_16x16x32_bf16(a1, bf11, acc1, 0, 0, 0);\
    acc2 = __builtin_amdgcn_mfma_f32_16x16x32_bf16(a1, bf21, acc2, 0, 0, 0);\
    acc3 = __builtin_amdgcn_mfma_f32_16x16x32_bf16(a1, bf31, acc3, 0, 0, 0);\
    acc0 = __builtin_amdgcn_mfma_f32_16x16x32_bf16(a2, bf02, acc0, 0, 0, 0);\
    acc1 = __builtin_amdgcn_mfma_f32_16x16x32_bf16(a2, bf12, acc1, 0, 0, 0);\
    acc2 = __builtin_amdgcn_mfma_f32_16x16x32_bf16(a2, bf22, acc2, 0, 0, 0);\
    acc3 = __builtin_amdgcn_mfma_f32_16x16x32_bf16(a2, bf32, acc3, 0, 0, 0);\
    acc0 = __builtin_amdgcn_mfma_f32_16x16x32_bf16(a3, bf03, acc0, 0, 0, 0);\
    acc1 = __builtin_amdgcn_mfma_f32_16x16x32_bf16(a3, bf13, acc1, 0, 0, 0);\
    acc2 = __builtin_amdgcn_mfma_f32_16x16x32_bf16(a3, bf23, acc2, 0, 0, 0);\
    acc3 = __builtin_amdgcn_mfma_f32_16x16x32_bf16(a3, bf33, acc3, 0, 0, 0);\
    float gi_ = fsig(acc0[0]);                                              \
    float gf_ = fsig(acc1[0]);                                              \
    float gg_ = ftanh(acc2[0]);                                             \
    float go_ = fsig(acc3[0]);                                              \
    cst = gf_ * cst + gi_ * gg_;                                            \
    float hv = go_ * ftanh(cst);                                            \
    HOUT = f2bf(hv);                                                        \
    if (lane < 16) hbuf[cur ^ 1][cell] = HOUT;                              \
    __syncthreads();                                                        \
    cur ^= 1;                                                               \
  }

  for (int chunk = 0; chunk < 64; ++chunk) {
    const int tb = t0 + chunk * 8 * tstep;
    ushort4v p0 = *(const ushort4v*)(prow + (size_t)(tb)             * 512);
    ushort4v p1 = *(const ushort4v*)(prow + (size_t)(tb + 1 * tstep) * 512);
    ushort4v p2 = *(const ushort4v*)(prow + (size_t)(tb + 2 * tstep) * 512);
    ushort4v p3 = *(const ushort4v*)(prow + (size_t)(tb + 3 * tstep) * 512);
    ushort4v p4 = *(const ushort4v*)(prow + (size_t)(tb + 4 * tstep) * 512);
    ushort4v p5 = *(const ushort4v*)(prow + (size_t)(tb + 5 * tstep) * 512);
    ushort4v p6 = *(const ushort4v*)(prow + (size_t)(tb + 6 * tstep) * 512);
    ushort4v p7 = *(const ushort4v*)(prow + (size_t)(tb + 7 * tstep) * 512);
    unsigned short h0, h1, h2, h3, h4, h5, h6, h7;
    LSTM_STEP(p0, h0)
    LSTM_STEP(p1, h1)
    LSTM_STEP(p2, h2)
    LSTM_STEP(p3, h3)
    LSTM_STEP(p4, h4)
    LSTM_STEP(p5, h5)
    LSTM_STEP(p6, h6)
    LSTM_STEP(p7, h7)
    if (lane < 16) {
      orow[(size_t)(tb)             * 256] = h0;
      orow[(size_t)(tb + 1 * tstep) * 256] = h1;
      orow[(size_t)(tb + 2 * tstep) * 256] = h2;
      orow[(size_t)(tb + 3 * tstep) * 256] = h3;
      orow[(size_t)(tb + 4 * tstep) * 256] = h4;
      orow[(size_t)(tb + 5 * tstep) * 256] = h5;
      orow[(size_t)(tb + 6 * tstep) * 256] = h6;
      orow[(size_t)(tb + 7 * tstep) * 256] = h7;
    }
  }
#undef LSTM_STEP
}

// ---------------- logits: z[row] = gz[row] + m_row(bf16) . W[1024:1280] + bias ----
// grid 8192, block 256 (wave per row)
__global__ __launch_bounds__(256) void logits_kernel(
    const __hip_bfloat16* __restrict__ m, const float* __restrict__ W,
    const float* __restrict__ bias, const float* __restrict__ gz,
    float* __restrict__ z)
{
  const int row = blockIdx.x * 4 + (threadIdx.x >> 6);
  const int lane = threadIdx.x & 63;
  const unsigned short* mrow = (const unsigned short*)m + (size_t)row * 256;
  float acc = 0.f;
  #pragma unroll
  for (int i = 0; i < 4; ++i) acc += bf2f(mrow[lane + 64 * i]) * W[1024 + lane + 64 * i];
  #pragma unroll
  for (int off = 32; off; off >>= 1) acc += __shfl_xor(acc, off);
  if (lane == 0) z[row] = acc + gz[row] + bias[0];
}

// ---------------- softmax over t ----------------
// grid 64, block 512
__global__ __launch_bounds__(512) void softmax_t_kernel(
    const float* __restrict__ z, float* __restrict__ p)
{
  const int b = blockIdx.x, t = threadIdx.x;
  __shared__ float red[8], red2[8];
  float v = z[(size_t)b * 512 + t];
  float m = v;
  #pragma unroll
  for (int off = 32; off; off >>= 1) m = fmaxf(m, __shfl_xor(m, off));
  if ((t & 63) == 0) red[t >> 6] = m;
  __syncthreads();
  float M = red[0];
  #pragma unroll
  for (int i = 1; i < 8; ++i) M = fmaxf(M, red[i]);
  float e = expf(v - M);
  float s = e;
  #pragma unroll
  for (int off = 32; off; off >>= 1) s += __shfl_xor(s, off);
  if ((t & 63) == 0) red2[t >> 6] = s;
  __syncthreads();
  float S = red2[0];
  #pragma unroll
  for (int i = 1; i < 8; ++i) S += red2[i];
  p[(size_t)b * 512 + t] = e / S;
}

extern "C" void kernel_launch(void* const* d_in, const int* in_sizes, int n_in,
                              void* d_out, int out_size, void* d_ws, size_t ws_size,
                              hipStream_t stream)
{
  const float* c   = (const float*)d_in[0];
  const float* q   = (const float*)d_in[1];
  const float* wc  = (const float*)d_in[2];
  const float* bc  = (const float*)d_in[3];
  const float* wq  = (const float*)d_in[4];
  const float* bq  = (const float*)d_in[5];
  const float* wcq = (const float*)d_in[6];
  const float* bcq = (const float*)d_in[7];
  const float* l1f_Wih = (const float*)d_in[8];
  const float* l1f_Whh = (const float*)d_in[9];
  const float* l1f_bih = (const float*)d_in[10];
  const float* l1f_bhh = (const float*)d_in[11];
  const float* l1b_Wih = (const float*)d_in[12];
  const float* l1b_Whh = (const float*)d_in[13];
  const float* l1b_bih = (const float*)d_in[14];
  const float* l1b_bhh = (const float*)d_in[15];
  const float* l2f_Wih = (const float*)d_in[16];
  const float* l2f_Whh = (const float*)d_in[17];
  const float* l2f_bih = (const float*)d_in[18];
  const float* l2f_bhh = (const float*)d_in[19];
  const float* l2b_Wih = (const float*)d_in[20];
  const float* l2b_Whh = (const float*)d_in[21];
  const float* l2b_bih = (const float*)d_in[22];
  const float* l2b_bhh = (const float*)d_in[23];
  const float* W0 = (const float*)d_in[24];
  const float* b0 = (const float*)d_in[25];
  const float* W1 = (const float*)d_in[26];
  const float* b1 = (const float*)d_in[27];

  const size_t required = 137371648u;
  if (ws_size < required) return;

  char* wsb = (char*)d_ws;
  __hip_bfloat16* gbf = (__hip_bfloat16*)wsb;                  // 67,108,864 B
  __hip_bfloat16* m   = (__hip_bfloat16*)wsb;                  // alias (g dead after gemm1)
  __hip_bfloat16* m2  = (__hip_bfloat16*)(wsb + 33554432);     // alias
  __hip_bfloat16* pref = (__hip_bfloat16*)(wsb + 67108864);    // 33,554,432 B
  __hip_bfloat16* preb = (__hip_bfloat16*)(wsb + 100663296);   // 33,554,432 B
  float* gz0  = (float*)(wsb + 134217728);
  float* gz1  = gz0 + 32768;
  float* smax = gz1 + 32768;
  float* z    = smax + 32768;
  unsigned short* w1f = (unsigned short*)(wsb + 134742016);
  unsigned short* w1b = (unsigned short*)(wsb + 135790592);
  unsigned short* w2f = (unsigned short*)(wsb + 136839168);
  unsigned short* w2b = (unsigned short*)(wsb + 137101312);
  float* bs = (float*)(wsb + 137363456);   // [4][512]: l1f, l1b, l2f, l2b
  float* p1 = (float*)d_out;
  float* p2 = p1 + 32768;

  cvt_w_kernel<<<1288, 256, 0, stream>>>(l1f_Wih, l1b_Wih, l2f_Wih, l2b_Wih,
                                         l1f_bih, l1f_bhh, l1b_bih, l1b_bhh,
                                         l2f_bih, l2f_bhh, l2b_bih, l2b_bhh,
                                         w1f, w1b, w2f, w2b, bs);
  attn_kernel<<<dim3(64, 4), 256, 0, stream>>>(c, q, wc, bc, wq, bq, wcq, bcq,
                                               W0, W1, gbf, smax, gz0, gz1);
  batt_kernel<<<64, 256, 0, stream>>>(c, smax, W0, W1, gbf, gz0, gz1);

  gemm_mfma_kernel<<<dim3(256, 4, 2), 256, 0, stream>>>(
      gbf, w1f, w1b, bs, bs + 512, pref, preb, 1024);
  lstm_kernel<<<dim3(64, 2), 512, 0, stream>>>(pref, preb, l1f_Whh, l1b_Whh, m);

  logits_kernel<<<8192, 256, 0, stream>>>(m, W0, b0, gz0, z);
  softmax_t_kernel<<<64, 512, 0, stream>>>(z, p1);

  gemm_mfma_kernel<<<dim3(256, 4, 2), 256, 0, stream>>>(
      m, w2f, w2b, bs + 1024, bs + 1536, pref, preb, 256);
  lstm_kernel<<<dim3(64, 2), 512, 0, stream>>>(pref, preb, l2f_Whh, l2b_Whh, m2);

  logits_kernel<<<8192, 256, 0, stream>>>(m2, W1, b1, gz1, z);
  softmax_t_kernel<<<64, 512, 0, stream>>>(z, p2);
}

// Round 11
// 967.129 us; speedup vs baseline: 1.2899x; 1.2149x over previous
//
#include <hip/hip_runtime.h>
#include <hip/hip_bf16.h>
#include <cstdint>
#include <cstddef>

// Shapes: B=64, T=512, J=64, D=256, E=128, gdim=8E=1024, gates=4E=512
// ws layout (bytes), total 137,371,648 (~131 MiB):
//   [0,           67,108,864)  g bf16 (32768 x 1024)   -- dead after gemm1
//        aliased: m  bf16 (32768 x 256) at 0 ; m2 bf16 at 33,554,432
//   [67,108,864, 100,663,296)  pre_f bf16 (32768 x 512)  [cell][gate] layout
//   [100,663,296,134,217,728)  pre_b bf16 (32768 x 512)  [cell][gate] layout
//   [134,217,728,134,742,016)  gz0, gz1, smax, z (32768 fp32 each)
//   [134,742,016,135,790,592)  w1f bf16 (512x1024)
//   [135,790,592,136,839,168)  w1b bf16
//   [136,839,168,137,101,312)  w2f bf16 (512x256)
//   [137,101,312,137,363,456)  w2b bf16
//   [137,363,456,137,371,648)  bs[4][512] fp32 (bih+bhh, l1f/l1b/l2f/l2b)

typedef short short8v __attribute__((ext_vector_type(8)));
typedef float f32x4 __attribute__((ext_vector_type(4)));
typedef unsigned short ushort8v __attribute__((ext_vector_type(8)));
typedef unsigned short ushort4v __attribute__((ext_vector_type(4)));

static __device__ __forceinline__ float bf2f(unsigned short u) {
  return __uint_as_float(((unsigned int)u) << 16);
}
static __device__ __forceinline__ unsigned short f2bf(float f) {  // RNE
  unsigned int u = __float_as_uint(f);
  return (unsigned short)((u + 0x7FFFu + ((u >> 16) & 1u)) >> 16);
}
static __device__ __forceinline__ float fsig(float x) {
  return 1.f / (1.f + __expf(-x));
}
static __device__ __forceinline__ float ftanh(float x) {
  return 1.f - 2.f / (__expf(2.f * x) + 1.f);
}

// ---------------- weight pre-convert: 4x Wih fp32->bf16, bias sums ----------
__global__ __launch_bounds__(256) void cvt_w_kernel(
    const float* __restrict__ w1f, const float* __restrict__ w1b,
    const float* __restrict__ w2f, const float* __restrict__ w2b,
    const float* __restrict__ b1fi, const float* __restrict__ b1fh,
    const float* __restrict__ b1bi, const float* __restrict__ b1bh,
    const float* __restrict__ b2fi, const float* __restrict__ b2fh,
    const float* __restrict__ b2bi, const float* __restrict__ b2bh,
    unsigned short* __restrict__ d1f, unsigned short* __restrict__ d1b,
    unsigned short* __restrict__ d2f, unsigned short* __restrict__ d2b,
    float* __restrict__ bs)
{
  const int bid = blockIdx.x, tid = threadIdx.x;
  if (bid < 1280) {
    int idx = (bid * 256 + tid) * 4;
    const float* src;
    unsigned short* dst;
    int off;
    if (idx < 524288)        { src = w1f; dst = d1f; off = idx; }
    else if (idx < 1048576)  { src = w1b; dst = d1b; off = idx - 524288; }
    else if (idx < 1179648)  { src = w2f; dst = d2f; off = idx - 1048576; }
    else                     { src = w2b; dst = d2b; off = idx - 1179648; }
    float4 f = *(const float4*)(src + off);
    ushort4v v;
    v[0] = f2bf(f.x); v[1] = f2bf(f.y); v[2] = f2bf(f.z); v[3] = f2bf(f.w);
    *(ushort4v*)(dst + off) = v;
  } else {
    int bidx = (bid - 1280) * 256 + tid;   // 0..2047
    int which = bidx >> 9, col = bidx & 511;
    float v;
    if (which == 0)      v = b1fi[col] + b1fh[col];
    else if (which == 1) v = b1bi[col] + b1bh[col];
    else if (which == 2) v = b2fi[col] + b2fh[col];
    else                 v = b2bi[col] + b2bh[col];
    bs[bidx] = v;
  }
}

// ---------------- MFMA attention ----------------
// grid (64, 4) block 256 (4 waves). t-chunk = 128 rows, 8 t-tiles of 16;
// wave w owns tiles w and w+4. s = c_bf16 @ qhat^T (qhat = wcq*q + wc folds
// the c.wc bias into the MFMA) + qwq[j] + bc + bcq. Softmax in-register
// (16-lane-group shfl reduce over the D-frag layout), P through wave-private
// LDS transpose, c2q = P @ q via MFMA, fused epilogue writes g[256:768],
// smax, and the gz0/gz1 partial dots. Zero barriers in the main loop.
// LDS ~149 KB -> 1 block/CU.
__global__ __launch_bounds__(256) void attn_kernel(
    const float* __restrict__ c, const float* __restrict__ q,
    const float* __restrict__ wc, const float* __restrict__ bc,
    const float* __restrict__ wq, const float* __restrict__ bq,
    const float* __restrict__ wcq, const float* __restrict__ bcq,
    const float* __restrict__ W0, const float* __restrict__ W1,
    __hip_bfloat16* __restrict__ g, float* __restrict__ smax,
    float* __restrict__ gz0, float* __restrict__ gz1)
{
  __shared__ unsigned short cbf[128][264];  // c bf16 (A for S; cv in epilogue)
  __shared__ unsigned short qhb[64][264];   // qhat bf16 j-major (B for S)
  __shared__ unsigned short qtb[256][72];   // q bf16 d-major (B for c2q)
  __shared__ unsigned short Pbuf[4][16][72];// per-wave P transpose (A for c2q)
  __shared__ float qwqs[64];
  __shared__ float qwp[4][64];
  const int b = blockIdx.x, tid = threadIdx.x;
  const int wave = tid >> 6, lane = tid & 63;
  const int t0 = blockIdx.y * 128;
  unsigned short* gbase = (unsigned short*)g;

  // stage q -> qhat (j-major) + q (d-major)
  #pragma unroll
  for (int i = 0; i < 16; ++i) {
    int idx = tid + i * 256;               // 4096 float4
    int j = idx >> 6, d4 = (idx & 63) * 4;
    float4 v = *(const float4*)&q[((size_t)b * 64 + j) * 256 + d4];
    float4 w4 = *(const float4*)&wcq[d4];
    float4 c4 = *(const float4*)&wc[d4];
    qhb[j][d4 + 0] = f2bf(v.x * w4.x + c4.x);
    qhb[j][d4 + 1] = f2bf(v.y * w4.y + c4.y);
    qhb[j][d4 + 2] = f2bf(v.z * w4.z + c4.z);
    qhb[j][d4 + 3] = f2bf(v.w * w4.w + c4.w);
    qtb[d4 + 0][j] = f2bf(v.x);
    qtb[d4 + 1][j] = f2bf(v.y);
    qtb[d4 + 2][j] = f2bf(v.z);
    qtb[d4 + 3][j] = f2bf(v.w);
  }
  // stage c -> cbf + g[0:256]
  #pragma unroll
  for (int i = 0; i < 32; ++i) {
    int idx = tid + i * 256;               // 8192 float4
    int r = idx >> 6, d4 = (idx & 63) * 4;
    float4 v = *(const float4*)&c[((size_t)b * 512 + t0 + r) * 256 + d4];
    ushort4v u;
    u[0] = f2bf(v.x); u[1] = f2bf(v.y); u[2] = f2bf(v.z); u[3] = f2bf(v.w);
    *(ushort4v*)&cbf[r][d4] = u;
    *(ushort4v*)&gbase[((size_t)b * 512 + t0 + r) * 1024 + d4] = u;
  }
  __syncthreads();
  // qwq[j] partials: wave w covers d = w*64..+63
  {
    float s = 0.f;
    for (int dd = 0; dd < 64; ++dd) {
      int d = wave * 64 + dd;
      s += bf2f(qtb[d][lane]) * wq[d];
    }
    qwp[wave][lane] = s;
  }
  __syncthreads();
  if (tid < 64) qwqs[tid] = qwp[0][tid] + qwp[1][tid] + qwp[2][tid] + qwp[3][tid] + bq[0];
  __syncthreads();

  const int cl = lane & 15, kg = lane >> 4;
  const float sbias = bc[0] + bcq[0];

  #pragma unroll
  for (int half = 0; half < 2; ++half) {
    const int tt = wave + half * 4;
    const int rowb = tt * 16;
    // ---- S-phase: S[16t x 64j], K=256
    f32x4 acc[4] = {};
    #pragma unroll
    for (int kt = 0; kt < 8; ++kt) {
      short8v a = *(const short8v*)&cbf[rowb + cl][kt * 32 + kg * 8];
      #pragma unroll
      for (int jt = 0; jt < 4; ++jt) {
        short8v bq_ = *(const short8v*)&qhb[jt * 16 + cl][kt * 32 + kg * 8];
        acc[jt] = __builtin_amdgcn_mfma_f32_16x16x32_bf16(a, bq_, acc[jt], 0, 0, 0);
      }
    }
    #pragma unroll
    for (int jt = 0; jt < 4; ++jt) {
      float qadd = qwqs[jt * 16 + cl] + sbias;
      #pragma unroll
      for (int r = 0; r < 4; ++r) acc[jt][r] += qadd;
    }
    // ---- softmax over j (row r = 4*kg + reg lives in the 16-lane group)
    f32x4 mx = acc[0];
    #pragma unroll
    for (int jt = 1; jt < 4; ++jt)
      #pragma unroll
      for (int r = 0; r < 4; ++r) mx[r] = fmaxf(mx[r], acc[jt][r]);
    #pragma unroll
    for (int off = 1; off < 16; off <<= 1)
      #pragma unroll
      for (int r = 0; r < 4; ++r) mx[r] = fmaxf(mx[r], __shfl_xor(mx[r], off));
    f32x4 se = {0.f, 0.f, 0.f, 0.f};
    #pragma unroll
    for (int jt = 0; jt < 4; ++jt)
      #pragma unroll
      for (int r = 0; r < 4; ++r) {
        acc[jt][r] = __expf(acc[jt][r] - mx[r]);
        se[r] += acc[jt][r];
      }
    #pragma unroll
    for (int off = 1; off < 16; off <<= 1)
      #pragma unroll
      for (int r = 0; r < 4; ++r) se[r] += __shfl_xor(se[r], off);
    f32x4 inv;
    #pragma unroll
    for (int r = 0; r < 4; ++r) inv[r] = 1.f / se[r];
    #pragma unroll
    for (int jt = 0; jt < 4; ++jt)
      #pragma unroll
      for (int r = 0; r < 4; ++r)
        Pbuf[wave][4 * kg + r][jt * 16 + cl] = f2bf(acc[jt][r] * inv[r]);
    if (cl == 0) {
      #pragma unroll
      for (int r = 0; r < 4; ++r)
        smax[(size_t)b * 512 + t0 + rowb + 4 * kg + r] = mx[r];
    }
    // ---- c2q phase: C2Q[16t x 256d], K=64  (Pbuf wave-private, no barrier)
    f32x4 gz0p = {0.f, 0.f, 0.f, 0.f}, gz1p = {0.f, 0.f, 0.f, 0.f};
    for (int dt = 0; dt < 16; ++dt) {
      f32x4 ca = {0.f, 0.f, 0.f, 0.f};
      #pragma unroll
      for (int kt = 0; kt < 2; ++kt) {
        short8v pa = *(const short8v*)&Pbuf[wave][cl][kt * 32 + kg * 8];
        short8v qb_ = *(const short8v*)&qtb[dt * 16 + cl][kt * 32 + kg * 8];
        ca = __builtin_amdgcn_mfma_f32_16x16x32_bf16(pa, qb_, ca, 0, 0, 0);
      }
      int d = dt * 16 + cl;
      float w0a = W0[d], w0b_ = W0[256 + d], w0c2 = W0[512 + d];
      float w1a = W1[d], w1b2 = W1[256 + d], w1c2 = W1[512 + d];
      #pragma unroll
      for (int r = 0; r < 4; ++r) {
        int rloc = rowb + 4 * kg + r;
        float cv = bf2f(cbf[rloc][d]);
        float av = ca[r];
        float pr = cv * av;
        size_t gr = ((size_t)b * 512 + t0 + rloc) * 1024;
        gbase[gr + 256 + d] = f2bf(av);
        gbase[gr + 512 + d] = f2bf(pr);
        gz0p[r] += cv * w0a + av * w0b_ + pr * w0c2;
        gz1p[r] += cv * w1a + av * w1b2 + pr * w1c2;
      }
    }
    #pragma unroll
    for (int off = 1; off < 16; off <<= 1)
      #pragma unroll
      for (int r = 0; r < 4; ++r) {
        gz0p[r] += __shfl_xor(gz0p[r], off);
        gz1p[r] += __shfl_xor(gz1p[r], off);
      }
    if (cl == 0) {
      #pragma unroll
      for (int r = 0; r < 4; ++r) {
        size_t rw = (size_t)b * 512 + t0 + rowb + 4 * kg + r;
        gz0[rw] = gz0p[r];
        gz1[rw] = gz1p[r];
      }
    }
  }
}

// ---------------- b_att softmax over t, q2c, g[768:1024] bf16, gz tail ----------
// grid 64, block 256
__global__ __launch_bounds__(256) void batt_kernel(
    const float* __restrict__ c, const float* __restrict__ smax,
    const float* __restrict__ W0, const float* __restrict__ W1,
    __hip_bfloat16* __restrict__ g,
    float* __restrict__ gz0, float* __restrict__ gz1)
{
  __shared__ float sm[512];
  __shared__ float red[4], red2[4];
  __shared__ float q2c_s[256];
  const int b = blockIdx.x, tid = threadIdx.x;
  float v0 = smax[(size_t)b * 512 + tid];
  float v1 = smax[(size_t)b * 512 + tid + 256];
  float m = fmaxf(v0, v1);
  #pragma unroll
  for (int off = 32; off; off >>= 1) m = fmaxf(m, __shfl_xor(m, off));
  if ((tid & 63) == 0) red[tid >> 6] = m;
  __syncthreads();
  float M = fmaxf(fmaxf(red[0], red[1]), fmaxf(red[2], red[3]));
  float e0 = expf(v0 - M), e1 = expf(v1 - M);
  float ssum = e0 + e1;
  #pragma unroll
  for (int off = 32; off; off >>= 1) ssum += __shfl_xor(ssum, off);
  if ((tid & 63) == 0) red2[tid >> 6] = ssum;
  __syncthreads();
  float S = red2[0] + red2[1] + red2[2] + red2[3];
  sm[tid] = e0 / S;
  sm[tid + 256] = e1 / S;
  __syncthreads();
  float acc = 0.f;
  #pragma unroll 8
  for (int t = 0; t < 512; ++t) acc += sm[t] * c[((size_t)b * 512 + t) * 256 + tid];
  q2c_s[tid] = acc;
  __syncthreads();
  const int wave = tid >> 6, lane = tid & 63;
  float qv[4], w0c[4], w1c[4];
  #pragma unroll
  for (int r = 0; r < 4; ++r) {
    int d = lane + 64 * r;
    qv[r]  = q2c_s[d];
    w0c[r] = W0[768 + d];
    w1c[r] = W1[768 + d];
  }
  for (int t = wave; t < 512; t += 4) {
    size_t row = (size_t)b * 512 + t;
    float s0 = 0.f, s1 = 0.f;
    #pragma unroll
    for (int r = 0; r < 4; ++r) {
      int d = lane + 64 * r;
      float v = c[row * 256 + d];
      float gv = v * qv[r];
      g[row * 1024 + 768 + d] = __float2bfloat16(gv);
      s0 += gv * w0c[r];
      s1 += gv * w1c[r];
    }
    #pragma unroll
    for (int off = 32; off; off >>= 1) {
      s0 += __shfl_xor(s0, off);
      s1 += __shfl_xor(s1, off);
    }
    if (lane == 0) { gz0[row] += s0; gz1[row] += s1; }
  }
}

// ---------------- MFMA GEMM: pre[M,512] = Xbf16[M,K] @ Wbf16[512,K]^T + bs ------
// grid (M/128, 4, 2), block 256 (4 waves, each 64x64). BK=64. z picks f/b dir.
// Output PERMUTED: pre[row][(col&127)*4 + (col>>7)]  ([cell][gate]).
__global__ __launch_bounds__(256) void gemm_mfma_kernel(
    const __hip_bfloat16* __restrict__ Xg,
    const unsigned short* __restrict__ Wf, const unsigned short* __restrict__ Wb,
    const float* __restrict__ bsf, const float* __restrict__ bsb,
    __hip_bfloat16* __restrict__ Yf, __hip_bfloat16* __restrict__ Yb, int K)
{
  __shared__ unsigned short Xs[128 * 72];
  __shared__ unsigned short Ws[128 * 72];
  const unsigned short* X = (const unsigned short*)Xg;
  const unsigned short* W = blockIdx.z ? Wb : Wf;
  const float* bs = blockIdx.z ? bsb : bsf;
  __hip_bfloat16* Y = blockIdx.z ? Yb : Yf;
  const int tid = threadIdx.x;
  const int m0 = blockIdx.x * 128, n0 = blockIdx.y * 128;
  const int lane = tid & 63, wave = tid >> 6;
  const int wr = wave >> 1, wc = wave & 1;
  const int frow = lane & 15, fk = (lane >> 4) * 8;

  f32x4 acc[4][4] = {};
  for (int kt = 0; kt < K; kt += 64) {
    #pragma unroll
    for (int i = 0; i < 4; ++i) {
      int cidx = tid + 256 * i;          // 0..1023
      int row = cidx >> 3, kc = cidx & 7;
      *(ushort8v*)&Xs[row * 72 + kc * 8] =
          *(const ushort8v*)&X[(size_t)(m0 + row) * K + kt + kc * 8];
      *(ushort8v*)&Ws[row * 72 + kc * 8] =
          *(const ushort8v*)&W[(size_t)(n0 + row) * K + kt + kc * 8];
    }
    __syncthreads();
    #pragma unroll
    for (int kk = 0; kk < 64; kk += 32) {
      short8v a[4], bfr[4];
      #pragma unroll
      for (int i = 0; i < 4; ++i)
        a[i] = *(const short8v*)&Xs[(wr * 64 + i * 16 + frow) * 72 + kk + fk];
      #pragma unroll
      for (int j = 0; j < 4; ++j)
        bfr[j] = *(const short8v*)&Ws[(wc * 64 + j * 16 + frow) * 72 + kk + fk];
      #pragma unroll
      for (int i = 0; i < 4; ++i)
        #pragma unroll
        for (int j = 0; j < 4; ++j)
          acc[i][j] = __builtin_amdgcn_mfma_f32_16x16x32_bf16(a[i], bfr[j], acc[i][j], 0, 0, 0);
    }
    __syncthreads();
  }
  const int r0 = (lane >> 4) * 4;
  #pragma unroll
  for (int j = 0; j < 4; ++j) {
    int col = n0 + wc * 64 + j * 16 + (lane & 15);
    int colp = (col & 127) * 4 + (col >> 7);   // [cell][gate] permuted layout
    float bsum = bs[col];
    #pragma unroll
    for (int i = 0; i < 4; ++i) {
      int rowb = m0 + wr * 64 + i * 16 + r0;
      #pragma unroll
      for (int r = 0; r < 4; ++r)
        Y[(size_t)(rowb + r) * 512 + colp] = __float2bfloat16(acc[i][j][r] + bsum);
    }
  }
}

// ---------------- LSTM recurrence via MFMA, 8-step chunked I/O (r8 winner) ----
__global__ __launch_bounds__(512, 2) void lstm_kernel(
    const __hip_bfloat16* __restrict__ pre_f, const __hip_bfloat16* __restrict__ pre_b,
    const float* __restrict__ Whh_f, const float* __restrict__ Whh_b,
    __hip_bfloat16* __restrict__ out)
{
  const int b = blockIdx.x, dir = blockIdx.y;
  const unsigned short* __restrict__ pre =
      (const unsigned short*)(dir ? pre_b : pre_f);
  const float* __restrict__ Whh = dir ? Whh_b : Whh_f;
  const int off = dir ? 128 : 0;
  const int tid = threadIdx.x;
  const int wave = tid >> 6, lane = tid & 63;
  const int cl = lane & 15;            // col / cell-within-wave
  const int kg = lane >> 4;            // k-group 0..3
  const int cell = wave * 16 + cl;     // 0..127

#define LOAD_BF(Q, T, DST)                                            \
  {                                                                   \
    const float* wp = Whh + (size_t)(Q * 128 + cell) * 128 + T * 32 + kg * 8; \
    float4 f0 = *(const float4*)wp;                                   \
    float4 f1 = *(const float4*)(wp + 4);                             \
    DST[0] = (short)f2bf(f0.x); DST[1] = (short)f2bf(f0.y);           \
    DST[2] = (short)f2bf(f0.z); DST[3] = (short)f2bf(f0.w);           \
    DST[4] = (short)f2bf(f1.x); DST[5] = (short)f2bf(f1.y);           \
    DST[6] = (short)f2bf(f1.z); DST[7] = (short)f2bf(f1.w);           \
    asm volatile("" : "+v"(DST));                                     \
  }
  short8v bf00, bf01, bf02, bf03, bf10, bf11, bf12, bf13;
  short8v bf20, bf21, bf22, bf23, bf30, bf31, bf32, bf33;
  LOAD_BF(0, 0, bf00) LOAD_BF(0, 1, bf01) LOAD_BF(0, 2, bf02) LOAD_BF(0, 3, bf03)
  LOAD_BF(1, 0, bf10) LOAD_BF(1, 1, bf11) LOAD_BF(1, 2, bf12) LOAD_BF(1, 3, bf13)
  LOAD_BF(2, 0, bf20) LOAD_BF(2, 1, bf21) LOAD_BF(2, 2, bf22) LOAD_BF(2, 3, bf23)
  LOAD_BF(3, 0, bf30) LOAD_BF(3, 1, bf31) LOAD_BF(3, 2, bf32) LOAD_BF(3, 3, bf33)
#undef LOAD_BF

  __shared__ unsigned short hbuf[2][128];
  if (tid < 128) { hbuf[0][tid] = 0; hbuf[1][tid] = 0; }
  __syncthreads();

  const size_t base = (size_t)b * 512;
  const int tstep = dir ? -1 : 1;
  const int t0 = dir ? 511 : 0;
  const unsigned short* prow = pre + base * 512 + cell * 4;
  unsigned short* orow = (unsigned short*)out + base * 256 + off + cell;

  int cur = 0;
  float cst = 0.f;
  f32x4 acc0 = {0.f, 0.f, 0.f, 0.f};
  f32x4 acc1 = acc0, acc2 = acc0, acc3 = acc0;

#define LSTM_STEP(P, HOUT)                                                  \
  {                                                                         \
    const unsigned short* hb = hbuf[cur];                                   \
    short8v a0 = *(const short8v*)(hb +  0 + kg * 8);                       \
    short8v a1 = *(const short8v*)(hb + 32 + kg * 8);                       \
    short8v a2 = *(const short8v*)(hb + 64 + kg * 8);                       \
    short8v a3 = *(const short8v*)(hb + 96 + kg * 8);                       \
    acc0[0] = bf2f(P[0]); acc1[0] = bf2f(P[1]);                             \
    acc2[0] = bf2f(P[2]); acc3[0] = bf2f(P[3]);                             \
    acc0 = __builtin_amdgcn_mfma_f32_16x16x32_bf16(a0, bf00, acc0, 0, 0, 0);\
    acc1 = __builtin_amdgcn_mfma_f32_16x16x32_bf16(a0, bf10, acc1, 0, 0, 0);\
    acc2 = __builtin_amdgcn_mfma_f32_16x16x32_bf16(a0, bf20, acc2, 0, 0, 0);\
    acc3 = __builtin_amdgcn_mfma_f32_16x16x32_bf16(a0, bf30, acc3, 0, 0, 0);\
    acc0 = __builtin_amdgcn_mfma_f32_16x16x32_bf16(a1, bf01, acc0, 0, 0, 0);\
    acc1 = __builtin_amdgcn_mfma_f32_16x16x32_bf16(a1, bf11, acc1, 0, 0, 0);\
    acc2 = __builtin_amdgcn_mfma_f32_16x16x32_bf16(a1, bf21, acc2, 0, 0, 0);\
    acc3 = __builtin_amdgcn_mfma_f32_16x16x32_bf16(a1, bf31, acc3, 0, 0, 0);\
    acc0 = __builtin_amdgcn_mfma_f32_16x16x32_bf16(a2, bf02, acc0, 0, 0, 0);\
    acc1 = __builtin_amdgcn_mfma_f32_16x16x32_bf16(a2, bf12, acc1, 0, 0, 0);\
    acc2 = __builtin_amdgcn_mfma_f32_16x16x32_bf16(a2, bf22, acc2, 0, 0, 0);\
    acc3 = __builtin_amdgcn_mfma_f32_16x16x32_bf16(a2, bf32, acc3, 0, 0, 0);\
    acc0 = __builtin_amdgcn_mfma_f32_16x16x32_bf16(a3, bf03, acc0, 0, 0, 0);\
    acc1 = __builtin_amdgcn_mfma_f32_16x16x32_bf16(a3, bf13, acc1, 0, 0, 0);\
    acc2 = __builtin_amdgcn_mfma_f32_16x16x32_bf16(a3, bf23, acc2, 0, 0, 0);\
    acc3 = __builtin_amdgcn_mfma_f32_16x16x32_bf16(a3, bf33, acc3, 0, 0, 0);\
    float gi_ = fsig(acc0[0]);                                              \
    float gf_ = fsig(acc1[0]);                                              \
    float gg_ = ftanh(acc2[0]);                                             \
    float go_ = fsig(acc3[0]);                                              \
    cst = gf_ * cst + gi_ * gg_;                                            \
    float hv = go_ * ftanh(cst);                                            \
    HOUT = f2bf(hv);                                                        \
    if (lane < 16) hbuf[cur ^ 1][cell] = HOUT;                              \
    __syncthreads();                                                        \
    cur ^= 1;                                                               \
  }

  for (int chunk = 0; chunk < 64; ++chunk) {
    const int tb = t0 + chunk * 8 * tstep;
    ushort4v p0 = *(const ushort4v*)(prow + (size_t)(tb)             * 512);
    ushort4v p1 = *(const ushort4v*)(prow + (size_t)(tb + 1 * tstep) * 512);
    ushort4v p2 = *(const ushort4v*)(prow + (size_t)(tb + 2 * tstep) * 512);
    ushort4v p3 = *(const ushort4v*)(prow + (size_t)(tb + 3 * tstep) * 512);
    ushort4v p4 = *(const ushort4v*)(prow + (size_t)(tb + 4 * tstep) * 512);
    ushort4v p5 = *(const ushort4v*)(prow + (size_t)(tb + 5 * tstep) * 512);
    ushort4v p6 = *(const ushort4v*)(prow + (size_t)(tb + 6 * tstep) * 512);
    ushort4v p7 = *(const ushort4v*)(prow + (size_t)(tb + 7 * tstep) * 512);
    unsigned short h0, h1, h2, h3, h4, h5, h6, h7;
    LSTM_STEP(p0, h0)
    LSTM_STEP(p1, h1)
    LSTM_STEP(p2, h2)
    LSTM_STEP(p3, h3)
    LSTM_STEP(p4, h4)
    LSTM_STEP(p5, h5)
    LSTM_STEP(p6, h6)
    LSTM_STEP(p7, h7)
    if (lane < 16) {
      orow[(size_t)(tb)             * 256] = h0;
      orow[(size_t)(tb + 1 * tstep) * 256] = h1;
      orow[(size_t)(tb + 2 * tstep) * 256] = h2;
      orow[(size_t)(tb + 3 * tstep) * 256] = h3;
      orow[(size_t)(tb + 4 * tstep) * 256] = h4;
      orow[(size_t)(tb + 5 * tstep) * 256] = h5;
      orow[(size_t)(tb + 6 * tstep) * 256] = h6;
      orow[(size_t)(tb + 7 * tstep) * 256] = h7;
    }
  }
#undef LSTM_STEP
}

// ---------------- logits: z[row] = gz[row] + m_row(bf16) . W[1024:1280] + bias ----
__global__ __launch_bounds__(256) void logits_kernel(
    const __hip_bfloat16* __restrict__ m, const float* __restrict__ W,
    const float* __restrict__ bias, const float* __restrict__ gz,
    float* __restrict__ z)
{
  const int row = blockIdx.x * 4 + (threadIdx.x >> 6);
  const int lane = threadIdx.x & 63;
  const unsigned short* mrow = (const unsigned short*)m + (size_t)row * 256;
  float acc = 0.f;
  #pragma unroll
  for (int i = 0; i < 4; ++i) acc += bf2f(mrow[lane + 64 * i]) * W[1024 + lane + 64 * i];
  #pragma unroll
  for (int off = 32; off; off >>= 1) acc += __shfl_xor(acc, off);
  if (lane == 0) z[row] = acc + gz[row] + bias[0];
}

// ---------------- softmax over t ----------------
__global__ __launch_bounds__(512) void softmax_t_kernel(
    const float* __restrict__ z, float* __restrict__ p)
{
  const int b = blockIdx.x, t = threadIdx.x;
  __shared__ float red[8], red2[8];
  float v = z[(size_t)b * 512 + t];
  float m = v;
  #pragma unroll
  for (int off = 32; off; off >>= 1) m = fmaxf(m, __shfl_xor(m, off));
  if ((t & 63) == 0) red[t >> 6] = m;
  __syncthreads();
  float M = red[0];
  #pragma unroll
  for (int i = 1; i < 8; ++i) M = fmaxf(M, red[i]);
  float e = expf(v - M);
  float s = e;
  #pragma unroll
  for (int off = 32; off; off >>= 1) s += __shfl_xor(s, off);
  if ((t & 63) == 0) red2[t >> 6] = s;
  __syncthreads();
  float S = red2[0];
  #pragma unroll
  for (int i = 1; i < 8; ++i) S += red2[i];
  p[(size_t)b * 512 + t] = e / S;
}

extern "C" void kernel_launch(void* const* d_in, const int* in_sizes, int n_in,
                              void* d_out, int out_size, void* d_ws, size_t ws_size,
                              hipStream_t stream)
{
  const float* c   = (const float*)d_in[0];
  const float* q   = (const float*)d_in[1];
  const float* wc  = (const float*)d_in[2];
  const float* bc  = (const float*)d_in[3];
  const float* wq  = (const float*)d_in[4];
  const float* bq  = (const float*)d_in[5];
  const float* wcq = (const float*)d_in[6];
  const float* bcq = (const float*)d_in[7];
  const float* l1f_Wih = (const float*)d_in[8];
  const float* l1f_Whh = (const float*)d_in[9];
  const float* l1f_bih = (const float*)d_in[10];
  const float* l1f_bhh = (const float*)d_in[11];
  const float* l1b_Wih = (const float*)d_in[12];
  const float* l1b_Whh = (const float*)d_in[13];
  const float* l1b_bih = (const float*)d_in[14];
  const float* l1b_bhh = (const float*)d_in[15];
  const float* l2f_Wih = (const float*)d_in[16];
  const float* l2f_Whh = (const float*)d_in[17];
  const float* l2f_bih = (const float*)d_in[18];
  const float* l2f_bhh = (const float*)d_in[19];
  const float* l2b_Wih = (const float*)d_in[20];
  const float* l2b_Whh = (const float*)d_in[21];
  const float* l2b_bih = (const float*)d_in[22];
  const float* l2b_bhh = (const float*)d_in[23];
  const float* W0 = (const float*)d_in[24];
  const float* b0 = (const float*)d_in[25];
  const float* W1 = (const float*)d_in[26];
  const float* b1 = (const float*)d_in[27];

  const size_t required = 137371648u;
  if (ws_size < required) return;

  char* wsb = (char*)d_ws;
  __hip_bfloat16* gbf = (__hip_bfloat16*)wsb;
  __hip_bfloat16* m   = (__hip_bfloat16*)wsb;
  __hip_bfloat16* m2  = (__hip_bfloat16*)(wsb + 33554432);
  __hip_bfloat16* pref = (__hip_bfloat16*)(wsb + 67108864);
  __hip_bfloat16* preb = (__hip_bfloat16*)(wsb + 100663296);
  float* gz0  = (float*)(wsb + 134217728);
  float* gz1  = gz0 + 32768;
  float* smax = gz1 + 32768;
  float* z    = smax + 32768;
  unsigned short* w1f = (unsigned short*)(wsb + 134742016);
  unsigned short* w1b = (unsigned short*)(wsb + 135790592);
  unsigned short* w2f = (unsigned short*)(wsb + 136839168);
  unsigned short* w2b = (unsigned short*)(wsb + 137101312);
  float* bs = (float*)(wsb + 137363456);
  float* p1 = (float*)d_out;
  float* p2 = p1 + 32768;

  cvt_w_kernel<<<1288, 256, 0, stream>>>(l1f_Wih, l1b_Wih, l2f_Wih, l2b_Wih,
                                         l1f_bih, l1f_bhh, l1b_bih, l1b_bhh,
                                         l2f_bih, l2f_bhh, l2b_bih, l2b_bhh,
                                         w1f, w1b, w2f, w2b, bs);
  attn_kernel<<<dim3(64, 4), 256, 0, stream>>>(c, q, wc, bc, wq, bq, wcq, bcq,
                                               W0, W1, gbf, smax, gz0, gz1);
  batt_kernel<<<64, 256, 0, stream>>>(c, smax, W0, W1, gbf, gz0, gz1);

  gemm_mfma_kernel<<<dim3(256, 4, 2), 256, 0, stream>>>(
      gbf, w1f, w1b, bs, bs + 512, pref, preb, 1024);
  lstm_kernel<<<dim3(64, 2), 512, 0, stream>>>(pref, preb, l1f_Whh, l1b_Whh, m);

  logits_kernel<<<8192, 256, 0, stream>>>(m, W0, b0, gz0, z);
  softmax_t_kernel<<<64, 512, 0, stream>>>(z, p1);

  gemm_mfma_kernel<<<dim3(256, 4, 2), 256, 0, stream>>>(
      m, w2f, w2b, bs + 1024, bs + 1536, pref, preb, 256);
  lstm_kernel<<<dim3(64, 2), 512, 0, stream>>>(pref, preb, l2f_Whh, l2b_Whh, m2);

  logits_kernel<<<8192, 256, 0, stream>>>(m2, W1, b1, gz1, z);
  softmax_t_kernel<<<64, 512, 0, stream>>>(z, p2);
}